// Round 8
// baseline (805.860 us; speedup 1.0000x reference)
//
#include <hip/hip_runtime.h>
#include <math.h>

#define B 8
#define C 64
#define L 2048
#define CS 256
#define BCL  (B*C*L)    // 1048576
#define BCSL (B*CS*L)   // 4194304
#define HS 0.25f

typedef unsigned short u16;
typedef unsigned int   u32;
typedef __attribute__((ext_vector_type(8))) short sh8;
typedef __attribute__((ext_vector_type(4))) float f4;
typedef __attribute__((ext_vector_type(8))) unsigned short us8;
typedef __attribute__((ext_vector_type(4))) unsigned short us4;

__device__ __forceinline__ float gelu(float x) {
    return 0.5f * x * (1.0f + erff(x * 0.70710678118654752440f));
}
__device__ __forceinline__ u16 f2b(float f) {
    u32 u = __float_as_uint(f);
    u32 r = u + 0x7FFFu + ((u >> 16) & 1u);
    return (u16)(r >> 16);
}
__device__ __forceinline__ float b2f(u16 h) {
    return __uint_as_float(((u32)h) << 16);
}
__device__ __forceinline__ u32 encmax(float f) {
    u32 b = __float_as_uint(f);
    return (b & 0x80000000u) ? ~b : (b | 0x80000000u);
}
__device__ __forceinline__ float decmax(u32 u) {
    return __uint_as_float((u & 0x80000000u) ? (u ^ 0x80000000u) : ~u);
}

// batched weight-fragment loads (6 frags = 6 L2 loads in flight)
__device__ __forceinline__ void ldw_a6(const sh8* __restrict__ w, int cb, int g,
                                       int lane, sh8 (&A)[6]) {
    #pragma unroll
    for (int u = 0; u < 6; ++u) A[u] = w[((cb + u)*4 + g)*64 + lane];
}

// ======== shared ode_f conv phases (8 waves, NF=3 task split) ========
// waves 0-3 -> ocg=w, frags {0,1}; waves 4-7 -> ocg=w-4, frag {2}. Frags
// cover rows [0,48); guards zero everything >= n_valid or outside [0,L).
// Weight prefetch: caller loads A1a before the preceding barrier; body
// interleaves remaining batches with MFMA chunks and preloads A2 (conv2).

__device__ __forceinline__ void conv1_body(sh8 (&A1a)[6],
        const sh8* __restrict__ w1v, const sh8* __restrict__ w2v,
        const float* __restrict__ kb1, const float* __restrict__ cd,
        const u16 (*__restrict__ IN)[264], u16 (*__restrict__ H1)[72],
        int n_valid, int gp0, int nfbase, int nfcnt, int ocg12,
        int nlo, int quad, int lane, sh8 (&A2)[6])
{
    f4 a1[2];
    a1[0] = f4{0.f,0.f,0.f,0.f}; a1[1] = a1[0];
    sh8 A1b[6];
    auto chunk = [&](sh8 (&AA)[6], int cb) {
        #pragma unroll
        for (int u = 0; u < 6; ++u) {
            const int c = cb + u;
            const int kk = c >> 3, ic0 = (c & 7) << 5;
            #pragma unroll
            for (int k = 0; k < 2; ++k) {
                if (k < nfcnt) {
                    const int nf = nfbase + k;
                    sh8 Bv = *(const sh8*)&IN[nf*16 + nlo + kk][ic0 + quad*8];
                    a1[k] = __builtin_amdgcn_mfma_f32_16x16x32_bf16(AA[u], Bv, a1[k], 0, 0, 0);
                }
            }
        }
    };
    ldw_a6(w1v, 6, ocg12, lane, A1b);
    chunk(A1a, 0);
    ldw_a6(w1v, 12, ocg12, lane, A1a);
    chunk(A1b, 6);
    ldw_a6(w1v, 18, ocg12, lane, A1b);
    chunk(A1a, 12);
    ldw_a6(w2v, 0, ocg12, lane, A2);
    chunk(A1b, 18);
    const int oc0 = ocg12*16 + quad*4;
    #pragma unroll
    for (int k = 0; k < 2; ++k) {
        if (k < nfcnt) {
            int nf = nfbase + k;
            int p = nf*16 + nlo;
            int gp = gp0 + p;
            bool ok = (p < n_valid) && (gp >= 0) && (gp < L);
            us4 pk;
            #pragma unroll
            for (int reg = 0; reg < 4; ++reg) {
                int oc = oc0 + reg;
                float v = (1.f + cd[oc]) * (a1[k][reg] + kb1[oc]) + cd[64+oc];
                pk[reg] = ok ? f2b(gelu(v)) : (u16)0;
            }
            *(us4*)&H1[p][oc0] = pk;
        }
    }
}

__device__ __forceinline__ void conv2_body(sh8 (&A2)[6],
        const sh8* __restrict__ w3v, const float* __restrict__ kb2,
        const u16 (*__restrict__ H1)[72], u16 (*__restrict__ H2)[72],
        int n_valid, int gq0, int nfbase, int nfcnt, int ocg12, int wave,
        int nlo, int quad, int lane, sh8 (&A3)[12])
{
    f4 a2[2];
    a2[0] = f4{0.f,0.f,0.f,0.f}; a2[1] = a2[0];
    #pragma unroll
    for (int c = 0; c < 6; ++c) {
        int kk = c >> 1, ic0 = (c & 1) << 5;
        #pragma unroll
        for (int k = 0; k < 2; ++k) {
            if (k < nfcnt) {
                int nf = nfbase + k;
                sh8 Bv = *(const sh8*)&H1[nf*16 + nlo + kk][ic0 + quad*8];
                a2[k] = __builtin_amdgcn_mfma_f32_16x16x32_bf16(A2[c], Bv, a2[k], 0, 0, 0);
            }
        }
    }
    // conv3 weights in flight during the epilogue; drained at next barrier
    #pragma unroll
    for (int ii = 0; ii < 12; ++ii) {
        int c = ii >> 1, mf = ii & 1;
        A3[ii] = w3v[(c*16 + wave*2 + mf)*64 + lane];
    }
    const int oc0 = ocg12*16 + quad*4;
    #pragma unroll
    for (int k = 0; k < 2; ++k) {
        if (k < nfcnt) {
            int nf = nfbase + k;
            int q = nf*16 + nlo;
            int gq = gq0 + q;
            bool ok = (q < n_valid) && (gq >= 0) && (gq < L);
            us4 pk;
            #pragma unroll
            for (int reg = 0; reg < 4; ++reg)
                pk[reg] = ok ? f2b(gelu(a2[k][reg] + kb2[oc0 + reg])) : (u16)0;
            *(us4*)&H2[q][oc0] = pk;
        }
    }
}

template<int NFO>
__device__ __forceinline__ void conv3_body(sh8 (&A3)[12],
        const u16 (*__restrict__ H2)[72], f4 (&a3)[2][3], int nlo, int quad)
{
    #pragma unroll
    for (int mf = 0; mf < 2; ++mf)
        #pragma unroll
        for (int nf = 0; nf < NFO; ++nf) a3[mf][nf] = f4{0.f,0.f,0.f,0.f};
    #pragma unroll
    for (int c = 0; c < 6; ++c) {
        int kk = c >> 1, ic0 = (c & 1) << 5;
        sh8 Bf[3];
        #pragma unroll
        for (int nf = 0; nf < NFO; ++nf)
            Bf[nf] = *(const sh8*)&H2[nf*16 + nlo + kk][ic0 + quad*8];
        #pragma unroll
        for (int mf = 0; mf < 2; ++mf) {
            #pragma unroll
            for (int nf = 0; nf < NFO; ++nf)
                a3[mf][nf] = __builtin_amdgcn_mfma_f32_16x16x32_bf16(A3[c*2+mf], Bf[nf], a3[mf][nf], 0, 0, 0);
        }
    }
}

// ---------- weight prep ----------
__global__ __launch_bounds__(256) void prep_k(const float* __restrict__ w,
        u16* __restrict__ dst, int IC, int OC) {
    int idx = blockIdx.x * 256 + threadIdx.x;
    int OCG = OC >> 4;
    int j = idx & 7, lane = (idx >> 3) & 63, t = idx >> 9;
    int ocg = t % OCG, c = t / OCG;
    int oc = ocg * 16 + (lane & 15);
    int K = c * 32 + ((lane >> 4) & 3) * 8 + j;
    int kk = K / IC, ic = K % IC;
    dst[idx] = f2b(w[((size_t)oc * IC + ic) * 3 + kk]);
}

// ---------- all 25 cond vectors ----------
__global__ void cond25_k(const float* __restrict__ tw1, const float* __restrict__ tb1,
                         const float* __restrict__ tw2, const float* __restrict__ tb2,
                         const float* __restrict__ cw, const float* __restrict__ cb,
                         float* __restrict__ condall) {
    __shared__ float te1[16], te2[16];
    int tix = blockIdx.x;
    int tid = threadIdx.x;
    double add[6] = {0.0, 0.25/5.0, 3.0*0.25/10.0, 4.0*0.25/5.0, 8.0*0.25/9.0, 0.25};
    float t = (tix == 24) ? 1.0f : (float)((double)(tix / 6) * 0.25 + add[tix % 6]);
    if (tid < 16) te1[tid] = gelu(t * tw1[tid] + tb1[tid]);
    __syncthreads();
    if (tid < 16) {
        float s = tb2[tid];
        for (int k = 0; k < 16; ++k) s += te1[k] * tw2[tid*16+k];
        te2[tid] = s;
    }
    __syncthreads();
    float s = cb[tid];
    for (int j = 0; j < 16; ++j) s += te2[j] * cw[tid*16+j];
    condall[tix*128 + tid] = s;
}

// ======== kpair: stages (2P+1, 2P+2) of one RK step fused, T=32 ========
// eval1 computed over 38 rows [l0-3,l0+35) (input halo 44 rows, 1.19x
// recompute, bit-identical to the materialized values — proven round 3);
// s_new kept in LDS; eval2's combo rebuilt from globals + LDS s_new with
// original accumulation order and a single f2b -> bit-identical numerics.
// LDS 77.8KB -> 2 blocks/CU (round-3 regression mode avoided).
// P==2 keeps s5 LDS-only: compile-time skip of eval1's global store.
// EPI: 0 = store s_{2P+2}; 1 = y+yb update; 2 = yb update + permuted out.
template<int P, int EPI>
__global__ __launch_bounds__(512, 4) void kpair_k(
        const u16* __restrict__ ybr, u16* __restrict__ ybw,
        const u16* __restrict__ s1g, const u16* __restrict__ s2g,
        const u16* __restrict__ s3g, const u16* __restrict__ s4g,
        u16* __restrict__ sAout, u16* __restrict__ sBout,
        const u16* __restrict__ wp1, const float* __restrict__ kb1,
        const u16* __restrict__ wp2, const float* __restrict__ kb2,
        const u16* __restrict__ wp3, const float* __restrict__ kb3,
        const float* __restrict__ condall, int tix0,
        float* __restrict__ y, float* __restrict__ outp)
{
    __shared__ u16 CA[50][264];    // conv input (combo); rows 44..49 zero
    __shared__ u16 SNEW[38][264];  // eval1 output s_{2P+1}, rows base l0-3
    __shared__ u16 H1[50][72];
    __shared__ u16 H2[50][72];
    __shared__ u16 ypart[32][264]; // P==2 only
    const int tid = threadIdx.x;
    const int l0  = blockIdx.x * 32;
    const int b   = blockIdx.y;
    const int wave = tid >> 6, lane = tid & 63;
    const int nlo = lane & 15, quad = lane >> 4;
    const int ocg12  = wave & 3;
    const int nfbase = (wave < 4) ? 0 : 2;
    const int nfcnt  = (wave < 4) ? 2 : 1;
    const sh8* w1v = (const sh8*)wp1;
    const sh8* w2v = (const sh8*)wp2;
    const sh8* w3v = (const sh8*)wp3;

    const float cy1 = HS*(35.f/384.f), cy3 = HS*(500.f/1113.f),
                cy4 = HS*(125.f/192.f), cy5 = -HS*(2187.f/6784.f),
                cy6 = HS*(11.f/84.f);
    // combo-A coefficients (stage 2P): s_j weights, ascending j
    const float cA1 = (P==1) ? HS*(3.f/40.f) : (P==2) ? HS*(19372.f/6561.f) : 0.f;
    const float cA2 = (P==1) ? HS*(9.f/40.f) : (P==2) ? -HS*(25360.f/2187.f) : 0.f;
    const float cA3 = (P==2) ? HS*(64448.f/6561.f) : 0.f;
    const float cA4 = (P==2) ? -HS*(212.f/729.f) : 0.f;
    // combo-B coefficients (stage 2P+1): globals g1..g4, then LDS s_new last
    const float g1 = (P==1) ? HS*(44.f/45.f)  : (P==2) ? HS*(9017.f/3168.f) : 0.f;
    const float g2 = (P==1) ? -HS*(56.f/15.f) : (P==2) ? -HS*(355.f/33.f)  : 0.f;
    const float g3 = (P==2) ? HS*(46732.f/5247.f) : 0.f;
    const float g4 = (P==2) ? HS*(49.f/176.f) : 0.f;
    const float gl_ = (P==0) ? HS*(1.f/5.f) : (P==1) ? HS*(32.f/9.f) : -HS*(5103.f/18656.f);

    // one-time zeros
    for (int i2 = tid; i2 < 6*264; i2 += 512) CA[44 + i2/264][i2%264] = 0;
    if (tid < 144) H1[48 + tid/72][tid%72] = 0;
    else if (tid < 288) { int t = tid - 144; H2[48 + t/72][t%72] = 0; }

    // ---- stage combo-A over 44 rows, base l0-6 ----
    for (int idx = tid; idx < 44*32; idx += 512) {
        int r = idx >> 5, o = (idx & 31) * 8;
        int gl = l0 - 6 + r;
        us8 val;
        if (gl >= 0 && gl < L) {
            size_t a = ((size_t)b * L + gl) * 256 + o;
            us8 v0 = *(const us8*)(ybr + a);
            if (P == 0) {
                val = v0;
            } else {
                float f[8];
                #pragma unroll
                for (int j = 0; j < 8; ++j) f[j] = b2f(v0[j]);
                us8 v1 = *(const us8*)(s1g + a);
                #pragma unroll
                for (int j = 0; j < 8; ++j) f[j] += cA1 * b2f(v1[j]);
                us8 v2 = *(const us8*)(s2g + a);
                #pragma unroll
                for (int j = 0; j < 8; ++j) f[j] += cA2 * b2f(v2[j]);
                if (P == 2) {
                    us8 v3 = *(const us8*)(s3g + a);
                    #pragma unroll
                    for (int j = 0; j < 8; ++j) f[j] += cA3 * b2f(v3[j]);
                    us8 v4 = *(const us8*)(s4g + a);
                    #pragma unroll
                    for (int j = 0; j < 8; ++j) f[j] += cA4 * b2f(v4[j]);
                }
                #pragma unroll
                for (int j = 0; j < 8; ++j) val[j] = f2b(f[j]);
            }
        } else {
            #pragma unroll
            for (int j = 0; j < 8; ++j) val[j] = 0;
        }
        *(us8*)&CA[r][o] = val;
    }

    sh8 A1a[6], A2[6], A3[12];
    ldw_a6(w1v, 0, ocg12, lane, A1a);
    __syncthreads();

    // ---- eval1: s_{2P+1} over 38 rows ----
    conv1_body(A1a, w1v, w2v, kb1, condall + tix0*128, CA, H1,
               42, l0-5, nfbase, nfcnt, ocg12, nlo, quad, lane, A2);
    __syncthreads();
    conv2_body(A2, w3v, kb2, H1, H2, 40, l0-4, nfbase, nfcnt, ocg12, wave,
               nlo, quad, lane, A3);
    __syncthreads();
    {
        f4 a3[2][3];
        conv3_body<3>(A3, H2, a3, nlo, quad);
        #pragma unroll
        for (int mf = 0; mf < 2; ++mf) {
            const int oc0 = (wave*2 + mf)*16 + quad*4;
            #pragma unroll
            for (int nf = 0; nf < 3; ++nf) {
                const int m = nf*16 + nlo;
                const int gm = l0 - 3 + m;
                const bool ok = (gm >= 0) && (gm < L);
                us4 pk;
                #pragma unroll
                for (int reg = 0; reg < 4; ++reg)
                    pk[reg] = ok ? f2b(a3[mf][nf][reg] + kb3[oc0 + reg]) : (u16)0;
                if (m < 38) *(us4*)&SNEW[m][oc0] = pk;
                if (P < 2 && m >= 3 && m < 35)   // P==2: s5 stays LDS-only
                    *(us4*)(sAout + ((size_t)b*L + gm)*256 + oc0) = pk;
            }
        }
    }
    __syncthreads();

    // ---- combo-B over 38 rows, base l0-3 (writes CA rows 0..37) ----
    for (int idx = tid; idx < 38*32; idx += 512) {
        int r = idx >> 5, o = (idx & 31) * 8;
        int gl = l0 - 3 + r;
        us8 sv = *(const us8*)&SNEW[r][o];
        us8 val;
        if (gl >= 0 && gl < L) {
            size_t a = ((size_t)b * L + gl) * 256 + o;
            us8 v0 = *(const us8*)(ybr + a);
            float f[8];
            #pragma unroll
            for (int j = 0; j < 8; ++j) f[j] = b2f(v0[j]);
            us8 v1, v3, v4;
            if (P >= 1) {
                v1 = *(const us8*)(s1g + a);
                #pragma unroll
                for (int j = 0; j < 8; ++j) f[j] += g1 * b2f(v1[j]);
                us8 v2 = *(const us8*)(s2g + a);
                #pragma unroll
                for (int j = 0; j < 8; ++j) f[j] += g2 * b2f(v2[j]);
            }
            if (P == 2) {
                v3 = *(const us8*)(s3g + a);
                #pragma unroll
                for (int j = 0; j < 8; ++j) f[j] += g3 * b2f(v3[j]);
                v4 = *(const us8*)(s4g + a);
                #pragma unroll
                for (int j = 0; j < 8; ++j) f[j] += g4 * b2f(v4[j]);
            }
            #pragma unroll
            for (int j = 0; j < 8; ++j) f[j] += gl_ * b2f(sv[j]);
            #pragma unroll
            for (int j = 0; j < 8; ++j) val[j] = f2b(f[j]);
            if (P == 2 && r >= 3 && r < 35) {
                us8 ypk;
                #pragma unroll
                for (int j = 0; j < 8; ++j) {
                    float yp = cy1 * b2f(v1[j]);
                    yp += cy3 * b2f(v3[j]);
                    yp += cy4 * b2f(v4[j]);
                    yp += cy5 * b2f(sv[j]);
                    ypk[j] = f2b(yp);
                }
                *(us8*)&ypart[r - 3][o] = ypk;
            }
        } else {
            #pragma unroll
            for (int j = 0; j < 8; ++j) val[j] = 0;
        }
        *(us8*)&CA[r][o] = val;
    }
    ldw_a6(w1v, 0, ocg12, lane, A1a);
    __syncthreads();

    // ---- eval2: s_{2P+2} over 32 rows (original geometry) ----
    conv1_body(A1a, w1v, w2v, kb1, condall + (tix0+1)*128, CA, H1,
               36, l0-2, nfbase, nfcnt, ocg12, nlo, quad, lane, A2);
    __syncthreads();
    conv2_body(A2, w3v, kb2, H1, H2, 34, l0-1, nfbase, nfcnt, ocg12, wave,
               nlo, quad, lane, A3);
    __syncthreads();
    f4 a3[2][3];
    conv3_body<2>(A3, H2, a3, nlo, quad);

    // ---- epilogue ----
    if (EPI == 0) {
        #pragma unroll
        for (int mf = 0; mf < 2; ++mf) {
            int baseoc = (wave*2 + mf)*16 + quad*4;
            #pragma unroll
            for (int nf = 0; nf < 2; ++nf) {
                int pos = l0 + nf*16 + nlo;
                us4 pk;
                #pragma unroll
                for (int reg = 0; reg < 4; ++reg)
                    pk[reg] = f2b(a3[mf][nf][reg] + kb3[baseoc + reg]);
                *(us4*)(sBout + ((size_t)b*L + pos)*256 + baseoc) = pk;
            }
        }
    } else {
        #pragma unroll
        for (int mf = 0; mf < 2; ++mf) {
            int baseoc = (wave*2 + mf)*16 + quad*4;
            #pragma unroll
            for (int nf = 0; nf < 2; ++nf) {
                int pl = nf*16 + nlo;
                int pos = l0 + pl;
                us4 yp4 = *(const us4*)&ypart[pl][baseoc];
                us4 pk;
                #pragma unroll
                for (int reg = 0; reg < 4; ++reg) {
                    int oc = baseoc + reg;
                    size_t idx = ((size_t)b*CS + oc)*L + pos;
                    float s6 = a3[mf][nf][reg] + kb3[oc];
                    float yv = y[idx] + b2f(yp4[reg]) + cy6 * s6;
                    pk[reg] = f2b(yv);
                    if (EPI == 1) y[idx] = yv;
                    if (EPI == 2) {
                        size_t oidx = (((size_t)(oc >> 6)*B + b)*64 + (oc & 63))*L + pos;
                        outp[oidx] = yv;
                    }
                }
                *(us4*)(ybw + ((size_t)b*L + pos)*256 + baseoc) = pk;
            }
        }
    }
}

// ======== ec: dx = ode_f(1.0, yb_final), ecloss inner product ========
__global__ __launch_bounds__(512, 4) void ec_k(const u16* __restrict__ ybin,
        const u16* __restrict__ wp1, const float* __restrict__ kb1,
        const u16* __restrict__ wp2, const float* __restrict__ kb2,
        const u16* __restrict__ wp3, const float* __restrict__ kb3,
        const float* __restrict__ condall,
        const float* __restrict__ stacked, double* __restrict__ inner)
{
    __shared__ u16 CA[50][264];
    __shared__ u16 H1[50][72];
    __shared__ u16 H2[50][72];
    __shared__ double sred[8];
    const int tid = threadIdx.x;
    const int l0  = blockIdx.x * 32;
    const int b   = blockIdx.y;
    const int wave = tid >> 6, lane = tid & 63;
    const int nlo = lane & 15, quad = lane >> 4;
    const int ocg12  = wave & 3;
    const int nfbase = (wave < 4) ? 0 : 2;
    const int nfcnt  = (wave < 4) ? 2 : 1;
    const sh8* w1v = (const sh8*)wp1;
    const sh8* w2v = (const sh8*)wp2;
    const sh8* w3v = (const sh8*)wp3;

    for (int i2 = tid; i2 < 12*264; i2 += 512) CA[38 + i2/264][i2%264] = 0;
    if (tid < 144) H1[48 + tid/72][tid%72] = 0;
    else if (tid < 288) { int t = tid - 144; H2[48 + t/72][t%72] = 0; }

    for (int idx = tid; idx < 38*32; idx += 512) {
        int r = idx >> 5, o = (idx & 31) * 8;
        int gl = l0 - 3 + r;
        us8 v;
        if (gl >= 0 && gl < L) {
            v = *(const us8*)(ybin + ((size_t)b*L + gl)*256 + o);
        } else {
            #pragma unroll
            for (int j = 0; j < 8; ++j) v[j] = 0;
        }
        *(us8*)&CA[r][o] = v;
    }
    sh8 A1a[6], A2[6], A3[12];
    ldw_a6(w1v, 0, ocg12, lane, A1a);
    __syncthreads();
    conv1_body(A1a, w1v, w2v, kb1, condall + 24*128, CA, H1,
               36, l0-2, nfbase, nfcnt, ocg12, nlo, quad, lane, A2);
    __syncthreads();
    conv2_body(A2, w3v, kb2, H1, H2, 34, l0-1, nfbase, nfcnt, ocg12, wave,
               nlo, quad, lane, A3);
    __syncthreads();
    f4 a3[2][3];
    conv3_body<2>(A3, H2, a3, nlo, quad);

    double acc = 0.0;
    #pragma unroll
    for (int mf = 0; mf < 2; ++mf)
        #pragma unroll
        for (int nf = 0; nf < 2; ++nf) {
            int pos = l0 + nf*16 + nlo;
            #pragma unroll
            for (int reg = 0; reg < 4; ++reg) {
                int oc = (wave*2 + mf)*16 + quad*4 + reg;
                size_t idx = ((size_t)b*CS + oc)*L + pos;
                float dx = a3[mf][nf][reg] + kb3[oc];
                acc += (double)stacked[idx] * (double)dx;
            }
        }
    #pragma unroll
    for (int off = 32; off > 0; off >>= 1) acc += __shfl_down(acc, off, 64);
    if (lane == 0) sred[wave] = acc;
    __syncthreads();
    if (tid == 0) {
        double s = 0.0;
        #pragma unroll
        for (int w = 0; w < 8; ++w) s += sred[w];
        atomicAdd(&inner[b], s);
    }
}

// ---------- wavelet part ----------
__global__ __launch_bounds__(256) void mlp_k(const u32* __restrict__ bm,
    const float* __restrict__ sw1, const float* __restrict__ sb1,
    const float* __restrict__ sw2, const float* __restrict__ sb2,
    const float* __restrict__ sw3, const float* __restrict__ sb3,
    float* __restrict__ filt) {
    __shared__ float m[8][64], f1[8][32], f2[8][32], raw[8][16], nrm[8][2];
    int tid = threadIdx.x;
    for (int i = tid; i < 512; i += 256) m[i >> 6][i & 63] = decmax(bm[i]);
    __syncthreads();
    {
        int b = tid >> 5, h = tid & 31;
        float s = sb1[h];
        for (int c = 0; c < 64; ++c) s += m[b][c] * sw1[h*64+c];
        f1[b][h] = gelu(s);
    }
    __syncthreads();
    {
        int b = tid >> 5, h = tid & 31;
        float s = sb2[h];
        for (int k = 0; k < 32; ++k) s += f1[b][k] * sw2[h*32+k];
        f2[b][h] = gelu(s);
    }
    __syncthreads();
    if (tid < 128) {
        int b = tid >> 4, j = tid & 15;
        float s = sb3[j];
        for (int k = 0; k < 32; ++k) s += f2[b][k] * sw3[j*32+k];
        raw[b][j] = s;
    }
    __syncthreads();
    if (tid < 16) {
        int b = tid >> 1, half = tid & 1;
        float s = 0.f;
        for (int j = 0; j < 8; ++j) { float v = raw[b][half*8+j]; s += v*v; }
        nrm[b][half] = sqrtf(s);
    }
    __syncthreads();
    if (tid < 16) {
        int half = tid >> 3;
        float s = 0.f;
        for (int b = 0; b < 8; ++b) s += raw[b][tid] / nrm[b][half];
        filt[tid] = s * 0.125f;
    }
}

__global__ __launch_bounds__(256) void wconv_k(const float* __restrict__ ap,
    const float* __restrict__ filt, float* __restrict__ apOut,
    float* __restrict__ stacked, int lev, u32* __restrict__ bmaxn) {
    __shared__ float f[16];
    __shared__ float red[256];
    if (threadIdx.x < 16) f[threadIdx.x] = filt[threadIdx.x];
    __syncthreads();
    size_t idx = (size_t)blockIdx.x * 256 + threadIdx.x;
    int l = (int)(idx & 2047);
    size_t bc = idx >> 11;
    int c = (int)(bc & 63), b = (int)(bc >> 6);
    const float* row = ap + (bc << 11);
    float lo = 0.f, hi = 0.f;
    #pragma unroll
    for (int k = 0; k < 8; ++k) {
        int mI = l + k - 3;
        mI = mI < 0 ? -mI : (mI >= L ? 2*L - 2 - mI : mI);
        float v = row[mI];
        lo += v * f[k];
        hi += v * f[8+k];
    }
    stacked[((size_t)b * CS + (size_t)(lev+1) * 64 + c) * L + l] = hi;
    if (bmaxn) {
        apOut[idx] = lo;
        red[threadIdx.x] = lo;
        __syncthreads();
        for (int s = 128; s > 0; s >>= 1) {
            if (threadIdx.x < s) red[threadIdx.x] = fmaxf(red[threadIdx.x], red[threadIdx.x + s]);
            __syncthreads();
        }
        if (threadIdx.x == 0) atomicMax(&bmaxn[blockIdx.x >> 3], encmax(red[0]));
    }
}

__global__ __launch_bounds__(256) void copyx_k(const float* __restrict__ x,
        float* __restrict__ st, u32* __restrict__ bmax0) {
    __shared__ float red[256];
    size_t i = (size_t)blockIdx.x * 256 + threadIdx.x;
    size_t b = i >> 17, rem = i & 131071;
    float v = x[i];
    st[b * ((size_t)CS*L) + rem] = v;
    red[threadIdx.x] = v;
    __syncthreads();
    for (int s = 128; s > 0; s >>= 1) {
        if (threadIdx.x < s) red[threadIdx.x] = fmaxf(red[threadIdx.x], red[threadIdx.x + s]);
        __syncthreads();
    }
    if (threadIdx.x == 0) atomicMax(&bmax0[blockIdx.x >> 3], encmax(red[0]));
}

// stacked fp32 [b][c][l] -> y fp32 (copy) + yb bf16 [b][l][c] (transpose)
__global__ __launch_bounds__(256) void tinit_k(const float* __restrict__ st,
        float* __restrict__ y, u16* __restrict__ yb) {
    __shared__ float t[64][65];
    const int tid = threadIdx.x;
    const int l0 = blockIdx.x * 64, c0 = blockIdx.y * 64, b = blockIdx.z;
    #pragma unroll
    for (int k = 0; k < 16; ++k) {
        int c = k * 4 + (tid >> 6), l = tid & 63;
        size_t idx = ((size_t)b*CS + c0 + c) * L + l0 + l;
        float v = st[idx];
        y[idx] = v;
        t[c][l] = v;
    }
    __syncthreads();
    #pragma unroll
    for (int k = 0; k < 16; ++k) {
        int p = k * 4 + (tid >> 6), ch = tid & 63;
        yb[((size_t)b * L + l0 + p) * 256 + c0 + ch] = f2b(t[ch][p]);
    }
}

__global__ void ecfin_k(const double* __restrict__ inner, float* __restrict__ out) {
    double s = 0.0;
    for (int b = 0; b < 8; ++b) s += inner[b] * inner[b];
    out[BCSL] = (float)(s / 8.0);
}

extern "C" void kernel_launch(void* const* d_in, const int* in_sizes, int n_in,
                              void* d_out, int out_size, void* d_ws, size_t ws_size,
                              hipStream_t stream) {
    const float* x   = (const float*)d_in[0];
    const float* sw1 = (const float*)d_in[1];
    const float* sb1 = (const float*)d_in[2];
    const float* sw2 = (const float*)d_in[3];
    const float* sb2 = (const float*)d_in[4];
    const float* sw3 = (const float*)d_in[5];
    const float* sb3 = (const float*)d_in[6];
    const float* tw1 = (const float*)d_in[7];
    const float* tb1 = (const float*)d_in[8];
    const float* tw2 = (const float*)d_in[9];
    const float* tb2 = (const float*)d_in[10];
    const float* cw  = (const float*)d_in[11];
    const float* cb  = (const float*)d_in[12];
    const float* k1  = (const float*)d_in[13];
    const float* kb1 = (const float*)d_in[14];
    const float* k2  = (const float*)d_in[15];
    const float* kb2 = (const float*)d_in[16];
    const float* k3  = (const float*)d_in[17];
    const float* kb3 = (const float*)d_in[18];
    float* out = (float*)d_out;

    char* cur = (char*)d_ws;
    auto alloc = [&](size_t bytes) { void* p = cur; cur += (bytes + 255) & ~(size_t)255; return p; };
    float* stacked = (float*)alloc(BCSL * 4);
    float* y       = (float*)alloc(BCSL * 4);
    u16*   yba     = (u16*)  alloc(BCSL * 2);
    u16*   ybb     = (u16*)  alloc(BCSL * 2);
    u16*   s1b     = (u16*)  alloc(BCSL * 2);
    u16*   s2b     = (u16*)  alloc(BCSL * 2);
    u16*   s3b     = (u16*)  alloc(BCSL * 2);
    u16*   s4b     = (u16*)  alloc(BCSL * 2);
    float* cond  = (float*)alloc(3200 * 4);
    double* inner = (double*)alloc(8 * 8);      // 256B slot
    u32* bmaxe   = (u32*)alloc(3 * 512 * 4);    // 3 levels of encoded row-maxes
    float* filt  = (float*)alloc(16 * 4);
    u16* wp1 = (u16*)alloc(49152 * 2);
    u16* wp2 = (u16*)alloc(12288 * 2);
    u16* wp3 = (u16*)alloc(49152 * 2);

    // zero inner (256B slot) + bmaxe (6144B); encmax(any real) > 0
    hipMemsetAsync(inner, 0, 256 + 3 * 512 * 4, stream);

    prep_k<<<192, 256, 0, stream>>>(k1, wp1, CS, C);
    prep_k<<<48,  256, 0, stream>>>(k2, wp2, C,  C);
    prep_k<<<192, 256, 0, stream>>>(k3, wp3, C,  CS);
    cond25_k<<<25, 128, 0, stream>>>(tw1, tb1, tw2, tb2, cw, cb, cond);

    // wavelet decomposition (s1b/s2b regions as fp32 scratch)
    copyx_k<<<4096, 256, 0, stream>>>(x, stacked, bmaxe);
    const float* apIn = x;
    float* apBuf[2] = {(float*)s1b, (float*)s2b};
    for (int lev = 0; lev < 3; ++lev) {
        mlp_k<<<1, 256, 0, stream>>>(bmaxe + lev*512, sw1, sb1, sw2, sb2, sw3, sb3, filt);
        float* apOut = apBuf[lev & 1];
        wconv_k<<<4096, 256, 0, stream>>>(apIn, filt, apOut, stacked, lev,
                                          (lev < 2) ? (bmaxe + (lev+1)*512) : nullptr);
        apIn = apOut;
    }
    tinit_k<<<dim3(32, 4, 8), 256, 0, stream>>>(stacked, y, yba);

    dim3 cg(64, 8);
    u16* ybs[2] = {yba, ybb};
    for (int i = 0; i < 4; ++i) {
        u16* ybr = ybs[i & 1];
        u16* ybw = ybs[(i & 1) ^ 1];     // double-buffered yb: no read/write race

        kpair_k<0, 0><<<cg, 512, 0, stream>>>(ybr, nullptr, s1b, s2b, s3b, s4b,
                s1b, s2b, wp1, kb1, wp2, kb2, wp3, kb3, cond, i*6+0, nullptr, nullptr);
        kpair_k<1, 0><<<cg, 512, 0, stream>>>(ybr, nullptr, s1b, s2b, s3b, s4b,
                s3b, s4b, wp1, kb1, wp2, kb2, wp3, kb3, cond, i*6+2, nullptr, nullptr);
        if (i < 3)
            kpair_k<2, 1><<<cg, 512, 0, stream>>>(ybr, ybw, s1b, s2b, s3b, s4b,
                    nullptr, nullptr, wp1, kb1, wp2, kb2, wp3, kb3, cond, i*6+4, y, nullptr);
        else
            kpair_k<2, 2><<<cg, 512, 0, stream>>>(ybr, ybw, s1b, s2b, s3b, s4b,
                    nullptr, nullptr, wp1, kb1, wp2, kb2, wp3, kb3, cond, i*6+4, y, out);
    }

    // dx = ode_f(1.0, yb_final) reads ybs[0] (written by step 3), ecloss fused
    ec_k<<<cg, 512, 0, stream>>>(ybs[0], wp1, kb1, wp2, kb2, wp3, kb3,
                                 cond, stacked, inner);
    ecfin_k<<<1, 1, 0, stream>>>(inner, out);
}